// Round 7
// baseline (20.780 us; speedup 1.0000x reference)
//
#include <hip/hip_runtime.h>

// HiddenMerger: the masked softmax's diagonal is exactly 0 for rows m>=1
// (diagonal masked with -2^32; exp underflows in fp32) and exactly 1/L for
// row 0 (every entry of row 0 rounds to exactly -2^32 -> uniform softmax).
//   out[b,0,d]    = (1/L) * sum_l hidden[b,l,d]
//   out[b,m>=1,d] = 0
// Two kernels, all streams CONTIGUOUS, all 256 CUs copy-shaped:
//   K1: block i owns 32 contiguous flat rows: streams 128 KB of hidden,
//       accumulates per-column partials -> 4 KB vector to d_ws[i]; zeroes
//       its 32 rows of out (contiguous 128 KB). 33.5 MB R + 34.5 MB W.
//   K2: per batch, fixed-order sum of 64 partial vectors (256 KB), scale
//       by 1/L, overwrite row 0. Bit-deterministic (no atomics).

namespace {
constexpr int B = 4;
constexpr int L = 2048;
constexpr int D = 1024;
constexpr int D4 = D / 4;             // 256 float4 per row
constexpr int ROWS_PB = 32;           // flat rows per K1 block
constexpr int NBLK = B * L / ROWS_PB; // 256 blocks
constexpr int NT = 512;               // K1 threads
constexpr int BPB = L / ROWS_PB;      // 64 K1 blocks per batch
}

__global__ __launch_bounds__(NT) void k_stream(const float* __restrict__ hidden,
                                               float* __restrict__ out,
                                               float* __restrict__ ws) {
    const int i = blockIdx.x;          // 0..255, owns flat rows [i*32, i*32+32)
    const int t = threadIdx.x;
    const int col = t & (D4 - 1);      // f4 column 0..255
    const int half = t >> 8;           // 0/1: row parity

    // Phase 1: contiguous streaming read of 32 rows; per-thread partial over
    // 16 rows of one f4 column. Consecutive threads -> consecutive 16 B.
    const float4* hp = reinterpret_cast<const float4*>(hidden) + (size_t)i * ROWS_PB * D4;
    float4 s = make_float4(0.f, 0.f, 0.f, 0.f);
#pragma unroll
    for (int j = 0; j < ROWS_PB / 2; ++j) {            // 16 iterations
        float4 v = hp[(size_t)(2 * j + half) * D4 + col];
        s.x += v.x; s.y += v.y; s.z += v.z; s.w += v.w;
    }

    // Phase 2: fold the two halves in LDS, write 4 KB partial vector to ws.
    __shared__ float4 red[NT];
    red[t] = s;
    __syncthreads();
    if (t < D4) {
        float4 o = red[t + D4];
        float4 m = red[t];
        m.x += o.x; m.y += o.y; m.z += o.z; m.w += o.w;
        reinterpret_cast<float4*>(ws)[(size_t)i * D4 + t] = m;
    }

    // Phase 3: zero this block's 32 output rows (contiguous 128 KB).
    float4* of4 = reinterpret_cast<float4*>(out) + (size_t)i * ROWS_PB * D4;
    const float4 zero = make_float4(0.f, 0.f, 0.f, 0.f);
#pragma unroll
    for (int k = 0; k < ROWS_PB * D4 / NT; ++k)        // 16 iterations
        of4[(size_t)k * NT + t] = zero;
}

__global__ __launch_bounds__(256) void k_finalize(const float* __restrict__ ws,
                                                  float* __restrict__ out) {
    const int b = blockIdx.x;          // batch 0..3
    const int t = threadIdx.x;         // f4 column 0..255
    const float4* wp = reinterpret_cast<const float4*>(ws) + (size_t)b * BPB * D4;
    float4 s = make_float4(0.f, 0.f, 0.f, 0.f);
#pragma unroll 8
    for (int j = 0; j < BPB; ++j) {    // fixed ascending order -> deterministic
        float4 v = wp[(size_t)j * D4 + t];
        s.x += v.x; s.y += v.y; s.z += v.z; s.w += v.w;
    }
    const float sc = 1.0f / (float)L;  // 2^-11, exact
    s.x *= sc; s.y *= sc; s.z *= sc; s.w *= sc;
    reinterpret_cast<float4*>(out + (size_t)b * L * D)[t] = s;
}

extern "C" void kernel_launch(void* const* d_in, const int* in_sizes, int n_in,
                              void* d_out, int out_size, void* d_ws, size_t ws_size,
                              hipStream_t stream) {
    const float* hidden = (const float*)d_in[0];
    float* out = (float*)d_out;
    float* ws = (float*)d_ws;          // needs 256*1024*4 B = 1 MB
    hipLaunchKernelGGL(k_stream, dim3(NBLK), dim3(NT), 0, stream, hidden, out, ws);
    hipLaunchKernelGGL(k_finalize, dim3(B), dim3(256), 0, stream, ws, out);
}

// Round 8
// 15.902 us; speedup vs baseline: 1.3068x; 1.3068x over previous
//
#include <hip/hip_runtime.h>

// HiddenMerger: the masked softmax's diagonal is exactly 0 for rows m>=1
// (diagonal masked with -2^32; exp underflows in fp32) and exactly 1/L for
// row 0 (every entry of row 0 rounds to exactly -2^32 -> uniform softmax).
//   out[b,0,d]    = (1/L) * sum_l hidden[b,l,d]
//   out[b,m>=1,d] = 0
// Single dispatch, 256 blocks x 512 threads, BOTH roles fused per block:
//   block = (slice s, half h): owns an 8-float4 (128 B = full line) column
//   slice of batch b over rows [h*1024, h*1024+1024), AND zeroes 32 flat
//   output rows; read + zero-store interleaved in one 16-iter loop so both
//   HBM directions stay in flight on every CU.
// The 2 half-partials per slice combine via device-scope atomics in d_ws:
//   atomicExch partials, ticket atomicAdd; the second arrival (odd parity,
//   correct for ANY initial ticket value) reads both halves in fixed order
//   and writes row 0. Bit-deterministic; atomics bypass per-XCD L2s.

namespace {
constexpr int B = 4;
constexpr int L = 2048;
constexpr int D = 1024;
constexpr int D4 = D / 4;                // 256 float4 per row
constexpr int NT = 512;
constexpr int CI = 8;                    // float4 per slice (128 B)
constexpr int CHUNKS = D4 / CI;          // 32 slices per batch
constexpr int NSLICE = CHUNKS * B;       // 128 slices
constexpr int NBLK = NSLICE * 2;         // 256 blocks (2 row-halves)
constexpr int HALF_ROWS = L / 2;         // 1024
constexpr int WAYS = NT / CI;            // 64 row-ways
constexpr int RITERS = HALF_ROWS / WAYS; // 16 read iters
constexpr int ZROWS = B * L / NBLK;      // 32 flat rows zeroed per block
constexpr int TICKET_OFF = 32 * 1024;    // byte offset of tickets in d_ws
}

__global__ __launch_bounds__(NT) void k_fused(const float* __restrict__ hidden,
                                              float* __restrict__ out,
                                              float* __restrict__ wsp,
                                              unsigned int* __restrict__ wst) {
    const int bid = blockIdx.x;
    const int t = threadIdx.x;
    const int s = bid >> 1;              // slice 0..127
    const int half = bid & 1;
    const int c = s & (CHUNKS - 1);      // 0..31
    const int b = s >> 5;                // 0..3
    const int ci = t & (CI - 1);         // 0..7
    const int ri = t >> 3;               // 0..63
    const int colf4 = c * CI + ci;

    const float4* hp = reinterpret_cast<const float4*>(hidden + (size_t)b * L * D)
                       + (size_t)half * HALF_ROWS * D4;
    float4* zp = reinterpret_cast<float4*>(out) + (size_t)bid * ZROWS * D4;
    const bool hasRow0 = ((bid & 63) == 0);   // block's first flat row is a batch row 0

    float4 acc = make_float4(0.f, 0.f, 0.f, 0.f);
    const float4 zero = make_float4(0.f, 0.f, 0.f, 0.f);
#pragma unroll
    for (int i = 0; i < RITERS; ++i) {
        float4 v = hp[(size_t)(ri + i * WAYS) * D4 + colf4];   // strided read
        const int zi = i * NT + t;                             // contiguous zero
        if (!(hasRow0 && zi < D4))
            zp[zi] = zero;
        acc.x += v.x; acc.y += v.y; acc.z += v.z; acc.w += v.w;
    }

    // LDS fold 64 row-ways -> 1 (fixed order).
    __shared__ float4 red[NT];
    red[t] = acc;
    __syncthreads();
#pragma unroll
    for (int sh = WAYS / 2; sh > 0; sh >>= 1) {
        if (ri < sh) {
            float4 o = red[(ri + sh) * CI + ci];
            float4 m = red[t];
            m.x += o.x; m.y += o.y; m.z += o.z; m.w += o.w;
            red[t] = m;
        }
        __syncthreads();
    }

    // Publish half-partial (device-scope atomics), then ticket.
    float* wp = wsp + ((size_t)s * 2 + half) * (CI * 4) + ci * 4;
    if (ri == 0) {
        float4 m = red[ci];
        atomicExch(wp + 0, m.x);
        atomicExch(wp + 1, m.y);
        atomicExch(wp + 2, m.z);
        atomicExch(wp + 3, m.w);
    }
    __syncthreads();                      // drains the exchs (vmcnt(0) before barrier)
    __shared__ unsigned int doCombine;
    if (t == 0)
        doCombine = atomicAdd(&wst[s], 1u) & 1u;  // 2nd arrival of this call -> odd
    __syncthreads();

    if (doCombine && ri == 0) {
        float* p0 = wsp + ((size_t)s * 2 + 0) * (CI * 4) + ci * 4;
        float* p1 = wsp + ((size_t)s * 2 + 1) * (CI * 4) + ci * 4;
        const float sc = 1.0f / (float)L;          // 2^-11, exact
        float4 r;
        r.x = (atomicAdd(p0 + 0, 0.f) + atomicAdd(p1 + 0, 0.f)) * sc;
        r.y = (atomicAdd(p0 + 1, 0.f) + atomicAdd(p1 + 1, 0.f)) * sc;
        r.z = (atomicAdd(p0 + 2, 0.f) + atomicAdd(p1 + 2, 0.f)) * sc;
        r.w = (atomicAdd(p0 + 3, 0.f) + atomicAdd(p1 + 3, 0.f)) * sc;
        reinterpret_cast<float4*>(out + (size_t)b * L * D)[colf4] = r;
    }
}

extern "C" void kernel_launch(void* const* d_in, const int* in_sizes, int n_in,
                              void* d_out, int out_size, void* d_ws, size_t ws_size,
                              hipStream_t stream) {
    const float* hidden = (const float*)d_in[0];
    float* out = (float*)d_out;
    float* wsp = (float*)d_ws;                                   // 32 KB partials
    unsigned int* wst = (unsigned int*)((char*)d_ws + TICKET_OFF); // 512 B tickets
    hipLaunchKernelGGL(k_fused, dim3(NBLK), dim3(NT), 0, stream, hidden, out, wsp, wst);
}